// Round 9
// baseline (216.036 us; speedup 1.0000x reference)
//
#include <hip/hip_runtime.h>
#include <math.h>

#define B_NUM 4
#define S_LEN 2048
#define D_DIM 1024
#define H_NUM 16
#define W_DIM 64

typedef float4 f4;
typedef _Float16 f16;
typedef f16 f16x8 __attribute__((ext_vector_type(8)));
typedef f16 f16x4 __attribute__((ext_vector_type(4)));
typedef float floatx4 __attribute__((ext_vector_type(4)));
typedef unsigned int u32;
typedef u32 u32x4 __attribute__((ext_vector_type(4)));

// Raw v_exp_f32 (2^x). Q is pre-scaled by 0.125*log2(e) in the qkv epilogue,
// so softmax needs no per-element multiply.
#if __has_builtin(__builtin_amdgcn_exp2f)
#define FEXP2(x) __builtin_amdgcn_exp2f(x)
#else
#define FEXP2(x) __expf((x) * 0.6931471805599453f)
#endif
#define QSCALE 0.18033688011f   /* 0.125 * log2(e) */

#define GLOAD_LDS16(gp, lp)                                                     \
    __builtin_amdgcn_global_load_lds(                                           \
        (const __attribute__((address_space(1))) void*)(gp),                    \
        (__attribute__((address_space(3))) void*)(lp), 16, 0, 0)

// ---------------------------------------------------------------------------
// Fused pre-pass: one launch does all three independent jobs.
//   blocks [0,4)        : per-batch mask compaction (prefix-sum -> fwdmap/cnt)
//   blocks [4,772)      : W fp32 -> W^T f16 (64x64 tiles, 3 matrices)
//   blocks [772,8964)   : x fp32 -> f16 cast
// Masked keys contribute exp(-10000)==0 -> skipping them is exact.
// ---------------------------------------------------------------------------
#define TR_BLOCKS   768          // 16 x 16 x 3
#define CAST_BLOCKS 8192         // B*S*D / 1024

__global__ __launch_bounds__(256) void prep_kernel(
    const int* __restrict__ mask, short* __restrict__ fwdmap,
    int* __restrict__ cnt,
    const float* __restrict__ Wq, const float* __restrict__ Wk,
    const float* __restrict__ Wv, f16* __restrict__ wt16,
    const float* __restrict__ x, f16* __restrict__ x16)
{
    __shared__ __align__(16) char smraw[64 * 68 * 4];
    const int bx  = blockIdx.x;
    const int tid = threadIdx.x;

    if (bx < 4) {
        // ---- mask compaction ----
        int* sc = (int*)smraw;
        const int b  = bx;
        const int t0 = tid * 8;
#pragma unroll
        for (int j = 0; j < 8; ++j) fwdmap[b * S_LEN + t0 + j] = 0;  // pad default
        int kept[8], c = 0;
#pragma unroll
        for (int j = 0; j < 8; ++j) {
            kept[j] = (mask[b * S_LEN + t0 + j] == 0);
            c += kept[j];
        }
        sc[tid] = c;
        __syncthreads();
        for (int off = 1; off < 256; off <<= 1) {
            int add = (tid >= off) ? sc[tid - off] : 0;
            __syncthreads();
            sc[tid] += add;
            __syncthreads();
        }
        int base = sc[tid] - c;
#pragma unroll
        for (int j = 0; j < 8; ++j)
            if (kept[j]) fwdmap[b * S_LEN + (base++)] = (short)(t0 + j);
        if (tid == 255) {
            cnt[b * 4 + 0] = sc[255];
            cnt[b * 4 + 1] = (sc[255] + 63) & ~63;
            cnt[b * 4 + 2] = (sc[255] + 127) & ~127;
            cnt[b * 4 + 3] = (sc[255] + 255) & ~255;
        }
    } else if (bx < 4 + TR_BLOCKS) {
        // ---- W transpose + cast ----
        float (*ts)[68] = (float(*)[68])smraw;
        const int idx = bx - 4;
        const int k0 = (idx & 15) * 64;
        const int n0 = ((idx >> 4) & 15) * 64;
        const int z  = idx >> 8;
        const float* Wsel = (z == 0) ? Wq : (z == 1) ? Wk : Wv;
        f16* outp = wt16 + (size_t)z * D_DIM * D_DIM;

        const int r  = tid >> 4;
        const int c4 = (tid & 15) * 4;
#pragma unroll
        for (int i = 0; i < 4; ++i) {
            f4 t = *(const f4*)&Wsel[(size_t)(k0 + r + i * 16) * D_DIM + n0 + c4];
            *(f4*)&ts[r + i * 16][c4] = t;
        }
        __syncthreads();
#pragma unroll
        for (int i = 0; i < 4; ++i) {
            int id2 = tid + i * 256;
            int nl = id2 >> 4;
            int k4 = (id2 & 15) * 4;
            f16x4 o;
#pragma unroll
            for (int j = 0; j < 4; ++j) o[j] = (f16)ts[k4 + j][nl];
            *(f16x4*)&outp[(size_t)(n0 + nl) * D_DIM + k0 + k4] = o;
        }
    } else {
        // ---- x -> f16 cast ----
        const size_t i = (size_t)(bx - 4 - TR_BLOCKS) * 256 + tid;
        f4 t = *(const f4*)&x[i * 4];
        f16x4 o;
        o[0] = (f16)t.x; o[1] = (f16)t.y; o[2] = (f16)t.z; o[3] = (f16)t.w;
        *(f16x4*)&x16[i * 4] = o;
    }
}

// ---------------------------------------------------------------------------
// QKV GEMM, f16 MFMA, BK=64, XOR-swizzled LDS (measured 0 bank conflicts).
// 2-phase double-buffer (round 5). Unchanged. Q scale = 0.125*log2(e) for
// attn's raw v_exp_f32.
//   Q -> (B,H,S,W) * QSCALE ; K -> (B,H,jc,W) ; V -> (B,H,W,jc)
// ---------------------------------------------------------------------------
#define QSTAGE(BUF, K0) do {                                                    \
    _Pragma("unroll") for (int it_ = 0; it_ < 4; ++it_) {                       \
        int chunk_ = wid * 4 + it_;                                             \
        GLOAD_LDS16(&x16[(size_t)arows[it_] * D_DIM + (K0) + scw],              \
                    &As[BUF][chunk_ * 512]);                                    \
        GLOAD_LDS16(&Bg[(size_t)(chunk_ * 8 + srow) * D_DIM + (K0) + scw],      \
                    &Bs[BUF][chunk_ * 512]);                                    \
    } } while (0)

#define QCOMPUTE(BUF) do {                                                      \
    _Pragma("unroll") for (int kh_ = 0; kh_ < 2; ++kh_) {                       \
        const int csw_ = ((kh_ * 4 + quad) ^ (lx & 7)) * 8;                     \
        f16x8 af_[4], bf_[4];                                                   \
        _Pragma("unroll") for (int tm_ = 0; tm_ < 4; ++tm_)                     \
            af_[tm_] = *(const f16x8*)&As[BUF][(wm * 64 + tm_ * 16 + lx) * 64 + csw_]; \
        _Pragma("unroll") for (int tn_ = 0; tn_ < 4; ++tn_)                     \
            bf_[tn_] = *(const f16x8*)&Bs[BUF][(wn * 64 + tn_ * 16 + lx) * 64 + csw_]; \
        _Pragma("unroll") for (int tm_ = 0; tm_ < 4; ++tm_)                     \
        _Pragma("unroll") for (int tn_ = 0; tn_ < 4; ++tn_)                     \
            acc[tm_][tn_] = __builtin_amdgcn_mfma_f32_16x16x32_f16(             \
                af_[tm_], bf_[tn_], acc[tm_][tn_], 0, 0, 0);                    \
    } } while (0)

#define QVM0BAR() do {                                                          \
    asm volatile("s_waitcnt vmcnt(0)" ::: "memory");                            \
    __builtin_amdgcn_s_barrier();                                               \
    } while (0)

__global__ __launch_bounds__(256) void qkv_mfma_kernel(
    const f16* __restrict__ x16, const f16* __restrict__ wt16,
    const float* __restrict__ bq, const float* __restrict__ bk,
    const float* __restrict__ bv, const short* __restrict__ fwdmap,
    const int* __restrict__ cnt,
    f16* __restrict__ Qo, f16* __restrict__ Ko, f16* __restrict__ Vo)
{
    __shared__ f16 As[2][128 * 64];
    __shared__ f16 Bs[2][128 * 64];

    const int tid  = threadIdx.x;
    const int lane = tid & 63;
    const int wid  = tid >> 6;
    const int lx   = lane & 15;
    const int quad = lane >> 4;
    const int wm   = wid >> 1;
    const int wn   = wid & 1;

    const int r0    = blockIdx.y * 128;
    const int nt    = blockIdx.x;
    const int midx  = nt >> 3;
    const int c0    = (nt & 7) * 128;
    const int bB    = r0 >> 11;               // batch (tiles never straddle)
    const int r0loc = r0 & (S_LEN - 1);

    if (midx > 0 && r0loc >= cnt[bB * 4 + 2]) return;   // block-uniform exit

    const f16* Bg = wt16 + (size_t)midx * D_DIM * D_DIM + (size_t)c0 * D_DIM;

    const int srow = lane >> 3;               // 0..7 within 8-row chunk
    const int scw  = ((lane & 7) ^ srow) * 8; // swizzled source k-chunk

    // A-row (global, batch-absolute) for each of this wave's 4 chunks
    int arows[4];
#pragma unroll
    for (int it = 0; it < 4; ++it) {
        int rl = (wid * 4 + it) * 8 + srow;   // 0..127 within tile
        arows[it] = (midx == 0)
            ? (r0 + rl)
            : (bB * S_LEN + (int)fwdmap[bB * S_LEN + r0loc + rl]);
    }

    floatx4 acc[4][4];
#pragma unroll
    for (int a = 0; a < 4; ++a)
#pragma unroll
        for (int b = 0; b < 4; ++b) { acc[a][b][0]=0.f; acc[a][b][1]=0.f; acc[a][b][2]=0.f; acc[a][b][3]=0.f; }

    // prologue: stage tile 0, wait, sync
    QSTAGE(0, 0);
    QVM0BAR();

    // steady state: stage t+1 under compute t
#pragma unroll 2
    for (int t = 0; t < 14; t += 2) {
        QSTAGE(1, (t + 1) * 64);
        QCOMPUTE(0);
        QVM0BAR();
        QSTAGE(0, (t + 2) * 64);
        QCOMPUTE(1);
        QVM0BAR();
    }
    // tiles 14, 15
    QSTAGE(1, 15 * 64);
    QCOMPUTE(0);
    QVM0BAR();
    QCOMPUTE(1);

    const float* bp = (midx == 0) ? bq : (midx == 1) ? bk : bv;
    float bias[4];
#pragma unroll
    for (int tn = 0; tn < 4; ++tn)
        bias[tn] = bp[c0 + wn * 64 + tn * 16 + lx];

    if (midx == 0) {
#pragma unroll
        for (int tm = 0; tm < 4; ++tm) {
            int s = r0loc + wm * 64 + tm * 16 + quad * 4;
#pragma unroll
            for (int tn = 0; tn < 4; ++tn) {
                int gc = c0 + wn * 64 + tn * 16 + lx;
                int h = gc >> 6, w = gc & 63;
                size_t base = (((size_t)(bB * H_NUM + h)) * S_LEN + s) * W_DIM + w;
#pragma unroll
                for (int rr = 0; rr < 4; ++rr)
                    Qo[base + (size_t)rr * W_DIM] =
                        (f16)((acc[tm][tn][rr] + bias[tn]) * QSCALE);
            }
        }
    } else if (midx == 1) {
#pragma unroll
        for (int tm = 0; tm < 4; ++tm) {
            int jc = r0loc + wm * 64 + tm * 16 + quad * 4;
#pragma unroll
            for (int tn = 0; tn < 4; ++tn) {
                int gc = c0 + wn * 64 + tn * 16 + lx;
                int h = gc >> 6, w = gc & 63;
                size_t base = (((size_t)(bB * H_NUM + h)) * S_LEN + jc) * W_DIM + w;
#pragma unroll
                for (int rr = 0; rr < 4; ++rr)
                    Ko[base + (size_t)rr * W_DIM] = (f16)(acc[tm][tn][rr] + bias[tn]);
            }
        }
    } else {
#pragma unroll
        for (int tm = 0; tm < 4; ++tm) {
            int jc = r0loc + wm * 64 + tm * 16 + quad * 4;
#pragma unroll
            for (int tn = 0; tn < 4; ++tn) {
                int gc = c0 + wn * 64 + tn * 16 + lx;
                int h = gc >> 6, w = gc & 63;
                f16x4 v;
#pragma unroll
                for (int rr = 0; rr < 4; ++rr) v[rr] = (f16)(acc[tm][tn][rr] + bias[tn]);
                *(f16x4*)&Vo[(((size_t)(bB * H_NUM + h)) * W_DIM + w) * S_LEN + jc] = v;
            }
        }
    }
}

// ---------------------------------------------------------------------------
// Flash attention over COMPACTED keys, S^T formulation, 2 q-tiles per wave.
// ROUND 9: depth-2 pipeline with COUNTED vmcnt (true T4). Round-8 showed the
// VALU cut helped less than the pipe arithmetic allows because the depth-1
// loop (vmcnt(0)/tile, issue->wait gap ~1 compute phase) re-exposes load
// latency. Now:
//  * 4 LDS buffers (64 KB): iter t stages tile t+2 into buf (t+2)&3.
//    WAR-free: that buffer was last read at tile t-2; every wave in iter t
//    has passed barrier(t-1), which no wave passes before all waves finish
//    compute(t-2). (3 buffers would race -- rejected.)
//  * counted waits: 4 loads/thread/tile, in-order retire -> before compute t
//    use vmcnt(8) (tiles t+1,t+2 in flight); tail: vmcnt(4) then vmcnt(0).
//    All guards block-uniform (ntile uniform). Issue->wait gap is now ~2
//    compute phases (~1500+ cyc) > worst-case load chain (~900 cyc).
//  * one barrier per tile (unchanged); compute body frozen from round 8
//    (ones-row-MFMA denominator, cvt_pkrtz, raw v_exp via pre-scaled Q).
// ---------------------------------------------------------------------------
#define ASTAGE(BUF, K0) do {                                                    \
    _Pragma("unroll") for (int it_ = 0; it_ < 2; ++it_) {                       \
        int idx_ = tid + it_ * 256;                                             \
        int row_ = idx_ >> 3, ci_ = idx_ & 7;                                   \
        int sc_  = (ci_ ^ (row_ & 7)) * 8;                                      \
        int key_ = ((row_ >> 5) << 5) | (((row_ >> 2) & 3) << 3)                \
                 | (((row_ >> 4) & 1) << 2) | (row_ & 3);                       \
        GLOAD_LDS16(&Kg[(size_t)((K0) + key_) * W_DIM + sc_],                   \
                    (f16*)Ks[BUF] + idx_ * 8);                                  \
        GLOAD_LDS16(&Vg[(size_t)row_ * S_LEN + (K0) + sc_],                     \
                    (f16*)Vs[BUF] + idx_ * 8);                                  \
    } } while (0)

#define ACOMPUTE(BUF, K0) do {                                                  \
    const bool tail_ = ((K0) + 64 > count);                                     \
    u32x4 pbu[2][2];                                                            \
    _Pragma("unroll") for (int n = 0; n < 4; ++n) {                             \
        f16x8 ka0 = *(const f16x8*)&Ks[BUF][n * 16 + lx][((0 + quad) ^ swz) * 8]; \
        f16x8 ka1 = *(const f16x8*)&Ks[BUF][n * 16 + lx][((4 + quad) ^ swz) * 8]; \
        const int kb = (K0) + ((n >> 1) << 5) + (quad << 3) + ((n & 1) << 2);   \
        _Pragma("unroll") for (int u = 0; u < 2; ++u) {                         \
            floatx4 s; s[0]=0.f; s[1]=0.f; s[2]=0.f; s[3]=0.f;                  \
            s = __builtin_amdgcn_mfma_f32_16x16x32_f16(ka0, qb[u][0], s, 0, 0, 0); \
            s = __builtin_amdgcn_mfma_f32_16x16x32_f16(ka1, qb[u][1], s, 0, 0, 0); \
            float p[4];                                                         \
            if (tail_) {                                                        \
                _Pragma("unroll") for (int r = 0; r < 4; ++r)                   \
                    p[r] = FEXP2((kb + r < count) ? s[r] : -1.0e4f);            \
            } else {                                                            \
                _Pragma("unroll") for (int r = 0; r < 4; ++r)                   \
                    p[r] = FEXP2(s[r]);                                         \
            }                                                                   \
            auto t0_ = __builtin_amdgcn_cvt_pkrtz(p[0], p[1]);                  \
            auto t1_ = __builtin_amdgcn_cvt_pkrtz(p[2], p[3]);                  \
            pbu[u][n >> 1][(n & 1) * 2 + 0] = __builtin_bit_cast(u32, t0_);     \
            pbu[u][n >> 1][(n & 1) * 2 + 1] = __builtin_bit_cast(u32, t1_);     \
        }                                                                       \
    }                                                                           \
    _Pragma("unroll") for (int wb = 0; wb < 4; ++wb) {                          \
        _Pragma("unroll") for (int m = 0; m < 2; ++m) {                         \
            f16x8 va = *(const f16x8*)&Vs[BUF][wb * 16 + lx][((m * 4 + quad) ^ swz) * 8]; \
            _Pragma("unroll") for (int u = 0; u < 2; ++u)                       \
                o[u][wb] = __builtin_amdgcn_mfma_f32_16x16x32_f16(              \
                    va, __builtin_bit_cast(f16x8, pbu[u][m]), o[u][wb], 0, 0, 0); \
        }                                                                       \
    }                                                                           \
    _Pragma("unroll") for (int m = 0; m < 2; ++m)                               \
        _Pragma("unroll") for (int u = 0; u < 2; ++u)                           \
            o1[u] = __builtin_amdgcn_mfma_f32_16x16x32_f16(                     \
                ones8, __builtin_bit_cast(f16x8, pbu[u][m]), o1[u], 0, 0, 0);   \
    } while (0)

__global__ __launch_bounds__(256) void attn_kernel(
    const f16* __restrict__ Q, const f16* __restrict__ Kc,
    const f16* __restrict__ Vct, const int* __restrict__ cnt,
    float* __restrict__ out)
{
    __shared__ f16 Ks[4][64][64];   // [buf][perm key][k]  swizzled 16B chunks
    __shared__ f16 Vs[4][64][64];   // [buf][w][key]       swizzled 16B chunks

    const int tid  = threadIdx.x;
    const int lane = tid & 63;
    const int wid  = tid >> 6;
    const int lx   = lane & 15;
    const int quad = lane >> 4;
    const int qt = blockIdx.x, h = blockIdx.y, bb = blockIdx.z;

    const int count = cnt[bb * 4 + 0];
    const int scp   = cnt[bb * 4 + 1];
    const int ntile = scp >> 6;

    const size_t hoff = ((size_t)(bb * H_NUM + h)) * S_LEN * W_DIM;
    const f16* Qg = Q + hoff + (size_t)qt * 128 * W_DIM;
    const f16* Kg = Kc + hoff;
    const f16* Vg = Vct + hoff;

    f16x8 qb[2][2];
#pragma unroll
    for (int u = 0; u < 2; ++u) {
        int qrow = u * 64 + wid * 16 + lx;
        qb[u][0] = *(const f16x8*)&Qg[(size_t)qrow * W_DIM + quad * 8];
        qb[u][1] = *(const f16x8*)&Qg[(size_t)qrow * W_DIM + 32 + quad * 8];
    }

    const f16x8 ones8 = {(f16)1.f, (f16)1.f, (f16)1.f, (f16)1.f,
                         (f16)1.f, (f16)1.f, (f16)1.f, (f16)1.f};

    floatx4 o[2][4];
    floatx4 o1[2];
#pragma unroll
    for (int u = 0; u < 2; ++u) {
        o1[u][0]=0.f; o1[u][1]=0.f; o1[u][2]=0.f; o1[u][3]=0.f;
#pragma unroll
        for (int wb = 0; wb < 4; ++wb) { o[u][wb][0]=0.f; o[u][wb][1]=0.f; o[u][wb][2]=0.f; o[u][wb][3]=0.f; }
    }

    const int swz = lx & 7;                    // read-side de-swizzle key

    // prologue: stage tiles 0 and 1 (depth-2)
    ASTAGE(0, 0);
    if (ntile > 1) ASTAGE(1, 64);

    // steady state: iter t stages t+2, counted-vmcnt waits only tile t's
    // loads (t+1, t+2 stay in flight across the barrier).
    for (int t = 0; t < ntile; ++t) {
        if (t + 2 < ntile) {
            ASTAGE((t + 2) & 3, (t + 2) * 64);
            asm volatile("s_waitcnt vmcnt(8)" ::: "memory");
        } else if (t + 1 < ntile) {
            asm volatile("s_waitcnt vmcnt(4)" ::: "memory");
        } else {
            asm volatile("s_waitcnt vmcnt(0)" ::: "memory");
        }
        __builtin_amdgcn_s_barrier();
        ACOMPUTE((t & 3), t * 64);
    }

#pragma unroll
    for (int u = 0; u < 2; ++u) {
        // o1 rows are all identical key-sums (ones A-operand); element 0 is
        // this lane's full denominator for its q. No cross-lane reduce.
        const float rl = 1.0f / o1[u][0];
        const int q = qt * 128 + u * 64 + wid * 16 + lx;
        const size_t base = ((size_t)bb * S_LEN + q) * D_DIM + h * W_DIM;
#pragma unroll
        for (int wb = 0; wb < 4; ++wb) {
            f4 r;
            r.x = o[u][wb][0] * rl;
            r.y = o[u][wb][1] * rl;
            r.z = o[u][wb][2] * rl;
            r.w = o[u][wb][3] * rl;
            *(f4*)&out[base + wb * 16 + quad * 4] = r;
        }
    }
}

// ---------------------------------------------------------------------------
extern "C" void kernel_launch(void* const* d_in, const int* in_sizes, int n_in,
                              void* d_out, int out_size, void* d_ws, size_t ws_size,
                              hipStream_t stream)
{
    const float* x    = (const float*)d_in[0];
    const float* Wq   = (const float*)d_in[1];
    const float* bq   = (const float*)d_in[2];
    const float* Wk   = (const float*)d_in[3];
    const float* bk   = (const float*)d_in[4];
    const float* Wv   = (const float*)d_in[5];
    const float* bv   = (const float*)d_in[6];
    const int*   mask = (const int*)d_in[7];
    float* out = (float*)d_out;

    const size_t per = (size_t)B_NUM * H_NUM * S_LEN * W_DIM;  // 8,388,608
    f16*   Q      = (f16*)d_ws;
    f16*   Kc     = Q + per;
    f16*   Vct    = Kc + per;
    f16*   x16    = Vct + per;
    f16*   wt16   = x16 + (size_t)(B_NUM * S_LEN) * D_DIM;
    int*   cnt    = (int*)(wt16 + (size_t)3 * D_DIM * D_DIM);
    short* fwdmap = (short*)(cnt + 4 * B_NUM);

    prep_kernel<<<4 + TR_BLOCKS + CAST_BLOCKS, 256, 0, stream>>>(
        mask, fwdmap, cnt, Wq, Wk, Wv, wt16, x, x16);
    qkv_mfma_kernel<<<dim3(24, 64), 256, 0, stream>>>(
        x16, wt16, bq, bk, bv, fwdmap, cnt, Q, Kc, Vct);
    attn_kernel<<<dim3(S_LEN / 128, H_NUM, B_NUM), 256, 0, stream>>>(
        Q, Kc, Vct, cnt, out);
}

// Round 10
// 215.933 us; speedup vs baseline: 1.0005x; 1.0005x over previous
//
#include <hip/hip_runtime.h>
#include <math.h>

#define B_NUM 4
#define S_LEN 2048
#define D_DIM 1024
#define H_NUM 16
#define W_DIM 64

typedef float4 f4;
typedef _Float16 f16;
typedef f16 f16x8 __attribute__((ext_vector_type(8)));
typedef f16 f16x4 __attribute__((ext_vector_type(4)));
typedef float floatx4 __attribute__((ext_vector_type(4)));
typedef unsigned int u32;
typedef u32 u32x4 __attribute__((ext_vector_type(4)));

// Raw v_exp_f32 (2^x). Q is pre-scaled by 0.125*log2(e) in the qkv epilogue,
// so softmax needs no per-element multiply.
#if __has_builtin(__builtin_amdgcn_exp2f)
#define FEXP2(x) __builtin_amdgcn_exp2f(x)
#else
#define FEXP2(x) __expf((x) * 0.6931471805599453f)
#endif
#define QSCALE 0.18033688011f   /* 0.125 * log2(e) */

#define GLOAD_LDS16(gp, lp)                                                     \
    __builtin_amdgcn_global_load_lds(                                           \
        (const __attribute__((address_space(1))) void*)(gp),                    \
        (__attribute__((address_space(3))) void*)(lp), 16, 0, 0)

// ---------------------------------------------------------------------------
// Fused pre-pass: one launch does all three independent jobs.
//   blocks [0,4)        : per-batch mask compaction (prefix-sum -> fwdmap/cnt)
//   blocks [4,772)      : W fp32 -> W^T f16 (64x64 tiles, 3 matrices)
//   blocks [772,8964)   : x fp32 -> f16 cast
// Masked keys contribute exp(-10000)==0 -> skipping them is exact.
// Streaming-BW-bound: ~66 MB total -> ~12 us; at its own roofline.
// ---------------------------------------------------------------------------
#define TR_BLOCKS   768          // 16 x 16 x 3
#define CAST_BLOCKS 8192         // B*S*D / 1024

__global__ __launch_bounds__(256) void prep_kernel(
    const int* __restrict__ mask, short* __restrict__ fwdmap,
    int* __restrict__ cnt,
    const float* __restrict__ Wq, const float* __restrict__ Wk,
    const float* __restrict__ Wv, f16* __restrict__ wt16,
    const float* __restrict__ x, f16* __restrict__ x16)
{
    __shared__ __align__(16) char smraw[64 * 68 * 4];
    const int bx  = blockIdx.x;
    const int tid = threadIdx.x;

    if (bx < 4) {
        // ---- mask compaction ----
        int* sc = (int*)smraw;
        const int b  = bx;
        const int t0 = tid * 8;
#pragma unroll
        for (int j = 0; j < 8; ++j) fwdmap[b * S_LEN + t0 + j] = 0;  // pad default
        int kept[8], c = 0;
#pragma unroll
        for (int j = 0; j < 8; ++j) {
            kept[j] = (mask[b * S_LEN + t0 + j] == 0);
            c += kept[j];
        }
        sc[tid] = c;
        __syncthreads();
        for (int off = 1; off < 256; off <<= 1) {
            int add = (tid >= off) ? sc[tid - off] : 0;
            __syncthreads();
            sc[tid] += add;
            __syncthreads();
        }
        int base = sc[tid] - c;
#pragma unroll
        for (int j = 0; j < 8; ++j)
            if (kept[j]) fwdmap[b * S_LEN + (base++)] = (short)(t0 + j);
        if (tid == 255) {
            cnt[b * 4 + 0] = sc[255];
            cnt[b * 4 + 1] = (sc[255] + 63) & ~63;
            cnt[b * 4 + 2] = (sc[255] + 127) & ~127;
            cnt[b * 4 + 3] = (sc[255] + 255) & ~255;
        }
    } else if (bx < 4 + TR_BLOCKS) {
        // ---- W transpose + cast ----
        float (*ts)[68] = (float(*)[68])smraw;
        const int idx = bx - 4;
        const int k0 = (idx & 15) * 64;
        const int n0 = ((idx >> 4) & 15) * 64;
        const int z  = idx >> 8;
        const float* Wsel = (z == 0) ? Wq : (z == 1) ? Wk : Wv;
        f16* outp = wt16 + (size_t)z * D_DIM * D_DIM;

        const int r  = tid >> 4;
        const int c4 = (tid & 15) * 4;
#pragma unroll
        for (int i = 0; i < 4; ++i) {
            f4 t = *(const f4*)&Wsel[(size_t)(k0 + r + i * 16) * D_DIM + n0 + c4];
            *(f4*)&ts[r + i * 16][c4] = t;
        }
        __syncthreads();
#pragma unroll
        for (int i = 0; i < 4; ++i) {
            int id2 = tid + i * 256;
            int nl = id2 >> 4;
            int k4 = (id2 & 15) * 4;
            f16x4 o;
#pragma unroll
            for (int j = 0; j < 4; ++j) o[j] = (f16)ts[k4 + j][nl];
            *(f16x4*)&outp[(size_t)(n0 + nl) * D_DIM + k0 + k4] = o;
        }
    } else {
        // ---- x -> f16 cast ----
        const size_t i = (size_t)(bx - 4 - TR_BLOCKS) * 256 + tid;
        f4 t = *(const f4*)&x[i * 4];
        f16x4 o;
        o[0] = (f16)t.x; o[1] = (f16)t.y; o[2] = (f16)t.z; o[3] = (f16)t.w;
        *(f16x4*)&x16[i * 4] = o;
    }
}

// ---------------------------------------------------------------------------
// QKV GEMM, f16 MFMA, BK=64, XOR-swizzled LDS (measured 0 bank conflicts).
// 2-phase double-buffer (round 5). Parked at ~67 us across depth-0/1
// variants (256^2 4-phase lost on makespan, round 1). Q scale =
// 0.125*log2(e) for attn's raw v_exp_f32.
//   Q -> (B,H,S,W) * QSCALE ; K -> (B,H,jc,W) ; V -> (B,H,W,jc)
// ---------------------------------------------------------------------------
#define QSTAGE(BUF, K0) do {                                                    \
    _Pragma("unroll") for (int it_ = 0; it_ < 4; ++it_) {                       \
        int chunk_ = wid * 4 + it_;                                             \
        GLOAD_LDS16(&x16[(size_t)arows[it_] * D_DIM + (K0) + scw],              \
                    &As[BUF][chunk_ * 512]);                                    \
        GLOAD_LDS16(&Bg[(size_t)(chunk_ * 8 + srow) * D_DIM + (K0) + scw],      \
                    &Bs[BUF][chunk_ * 512]);                                    \
    } } while (0)

#define QCOMPUTE(BUF) do {                                                      \
    _Pragma("unroll") for (int kh_ = 0; kh_ < 2; ++kh_) {                       \
        const int csw_ = ((kh_ * 4 + quad) ^ (lx & 7)) * 8;                     \
        f16x8 af_[4], bf_[4];                                                   \
        _Pragma("unroll") for (int tm_ = 0; tm_ < 4; ++tm_)                     \
            af_[tm_] = *(const f16x8*)&As[BUF][(wm * 64 + tm_ * 16 + lx) * 64 + csw_]; \
        _Pragma("unroll") for (int tn_ = 0; tn_ < 4; ++tn_)                     \
            bf_[tn_] = *(const f16x8*)&Bs[BUF][(wn * 64 + tn_ * 16 + lx) * 64 + csw_]; \
        _Pragma("unroll") for (int tm_ = 0; tm_ < 4; ++tm_)                     \
        _Pragma("unroll") for (int tn_ = 0; tn_ < 4; ++tn_)                     \
            acc[tm_][tn_] = __builtin_amdgcn_mfma_f32_16x16x32_f16(             \
                af_[tm_], bf_[tn_], acc[tm_][tn_], 0, 0, 0);                    \
    } } while (0)

#define QVM0BAR() do {                                                          \
    asm volatile("s_waitcnt vmcnt(0)" ::: "memory");                            \
    __builtin_amdgcn_s_barrier();                                               \
    } while (0)

__global__ __launch_bounds__(256) void qkv_mfma_kernel(
    const f16* __restrict__ x16, const f16* __restrict__ wt16,
    const float* __restrict__ bq, const float* __restrict__ bk,
    const float* __restrict__ bv, const short* __restrict__ fwdmap,
    const int* __restrict__ cnt,
    f16* __restrict__ Qo, f16* __restrict__ Ko, f16* __restrict__ Vo)
{
    __shared__ f16 As[2][128 * 64];
    __shared__ f16 Bs[2][128 * 64];

    const int tid  = threadIdx.x;
    const int lane = tid & 63;
    const int wid  = tid >> 6;
    const int lx   = lane & 15;
    const int quad = lane >> 4;
    const int wm   = wid >> 1;
    const int wn   = wid & 1;

    const int r0    = blockIdx.y * 128;
    const int nt    = blockIdx.x;
    const int midx  = nt >> 3;
    const int c0    = (nt & 7) * 128;
    const int bB    = r0 >> 11;               // batch (tiles never straddle)
    const int r0loc = r0 & (S_LEN - 1);

    if (midx > 0 && r0loc >= cnt[bB * 4 + 2]) return;   // block-uniform exit

    const f16* Bg = wt16 + (size_t)midx * D_DIM * D_DIM + (size_t)c0 * D_DIM;

    const int srow = lane >> 3;               // 0..7 within 8-row chunk
    const int scw  = ((lane & 7) ^ srow) * 8; // swizzled source k-chunk

    // A-row (global, batch-absolute) for each of this wave's 4 chunks
    int arows[4];
#pragma unroll
    for (int it = 0; it < 4; ++it) {
        int rl = (wid * 4 + it) * 8 + srow;   // 0..127 within tile
        arows[it] = (midx == 0)
            ? (r0 + rl)
            : (bB * S_LEN + (int)fwdmap[bB * S_LEN + r0loc + rl]);
    }

    floatx4 acc[4][4];
#pragma unroll
    for (int a = 0; a < 4; ++a)
#pragma unroll
        for (int b = 0; b < 4; ++b) { acc[a][b][0]=0.f; acc[a][b][1]=0.f; acc[a][b][2]=0.f; acc[a][b][3]=0.f; }

    // prologue: stage tile 0, wait, sync
    QSTAGE(0, 0);
    QVM0BAR();

    // steady state: stage t+1 under compute t
#pragma unroll 2
    for (int t = 0; t < 14; t += 2) {
        QSTAGE(1, (t + 1) * 64);
        QCOMPUTE(0);
        QVM0BAR();
        QSTAGE(0, (t + 2) * 64);
        QCOMPUTE(1);
        QVM0BAR();
    }
    // tiles 14, 15
    QSTAGE(1, 15 * 64);
    QCOMPUTE(0);
    QVM0BAR();
    QCOMPUTE(1);

    const float* bp = (midx == 0) ? bq : (midx == 1) ? bk : bv;
    float bias[4];
#pragma unroll
    for (int tn = 0; tn < 4; ++tn)
        bias[tn] = bp[c0 + wn * 64 + tn * 16 + lx];

    if (midx == 0) {
#pragma unroll
        for (int tm = 0; tm < 4; ++tm) {
            int s = r0loc + wm * 64 + tm * 16 + quad * 4;
#pragma unroll
            for (int tn = 0; tn < 4; ++tn) {
                int gc = c0 + wn * 64 + tn * 16 + lx;
                int h = gc >> 6, w = gc & 63;
                size_t base = (((size_t)(bB * H_NUM + h)) * S_LEN + s) * W_DIM + w;
#pragma unroll
                for (int rr = 0; rr < 4; ++rr)
                    Qo[base + (size_t)rr * W_DIM] =
                        (f16)((acc[tm][tn][rr] + bias[tn]) * QSCALE);
            }
        }
    } else if (midx == 1) {
#pragma unroll
        for (int tm = 0; tm < 4; ++tm) {
            int jc = r0loc + wm * 64 + tm * 16 + quad * 4;
#pragma unroll
            for (int tn = 0; tn < 4; ++tn) {
                int gc = c0 + wn * 64 + tn * 16 + lx;
                int h = gc >> 6, w = gc & 63;
                size_t base = (((size_t)(bB * H_NUM + h)) * S_LEN + jc) * W_DIM + w;
#pragma unroll
                for (int rr = 0; rr < 4; ++rr)
                    Ko[base + (size_t)rr * W_DIM] = (f16)(acc[tm][tn][rr] + bias[tn]);
            }
        }
    } else {
#pragma unroll
        for (int tm = 0; tm < 4; ++tm) {
            int jc = r0loc + wm * 64 + tm * 16 + quad * 4;
#pragma unroll
            for (int tn = 0; tn < 4; ++tn) {
                int gc = c0 + wn * 64 + tn * 16 + lx;
                int h = gc >> 6, w = gc & 63;
                f16x4 v;
#pragma unroll
                for (int rr = 0; rr < 4; ++rr) v[rr] = (f16)(acc[tm][tn][rr] + bias[tn]);
                *(f16x4*)&Vo[(((size_t)(bB * H_NUM + h)) * W_DIM + w) * S_LEN + jc] = v;
            }
        }
    }
}

// ---------------------------------------------------------------------------
// Flash attention over COMPACTED keys, S^T formulation, 2 q-tiles per wave.
// FINAL (round-8 measured-best configuration, 215.6 us total):
//  * direct global_load_lds staging, double-buffer, source-side K-row
//    permutation + XOR chunk swizzle (SQ_LDS_BANK_CONFLICT == 0 measured);
//  * one raw s_barrier per k-tile, vmcnt(0) fence (depth-2 counted-vmcnt
//    variant measured equal within noise -- simpler depth-1 kept);
//  * softmax on the matrix pipe: ones-row MFMA denominator (no cross-lane
//    reduce), cvt_pkrtz packing, raw v_exp via pre-scaled Q;
//  * PV as 16x16x32 via the in-register P-packing the K-permutation enables.
// Issue-mix model (per SIMD per k-tile slot): MFMA ~680 cyc + VALU ~800 +
// LDS ~760 of ~2400 -- pipes sum to ~93% of issue capacity; overlap levers
// null here, only instruction-count cuts move it.
// ---------------------------------------------------------------------------
#define ASTAGE(BUF, K0) do {                                                    \
    _Pragma("unroll") for (int it_ = 0; it_ < 2; ++it_) {                       \
        int idx_ = tid + it_ * 256;                                             \
        int row_ = idx_ >> 3, ci_ = idx_ & 7;                                   \
        int sc_  = (ci_ ^ (row_ & 7)) * 8;                                      \
        int key_ = ((row_ >> 5) << 5) | (((row_ >> 2) & 3) << 3)                \
                 | (((row_ >> 4) & 1) << 2) | (row_ & 3);                       \
        GLOAD_LDS16(&Kg[(size_t)((K0) + key_) * W_DIM + sc_],                   \
                    (f16*)Ks[BUF] + idx_ * 8);                                  \
        GLOAD_LDS16(&Vg[(size_t)row_ * S_LEN + (K0) + sc_],                     \
                    (f16*)Vs[BUF] + idx_ * 8);                                  \
    } } while (0)

#define ACOMPUTE(BUF, K0) do {                                                  \
    const bool tail_ = ((K0) + 64 > count);                                     \
    u32x4 pbu[2][2];                                                            \
    _Pragma("unroll") for (int n = 0; n < 4; ++n) {                             \
        f16x8 ka0 = *(const f16x8*)&Ks[BUF][n * 16 + lx][((0 + quad) ^ swz) * 8]; \
        f16x8 ka1 = *(const f16x8*)&Ks[BUF][n * 16 + lx][((4 + quad) ^ swz) * 8]; \
        const int kb = (K0) + ((n >> 1) << 5) + (quad << 3) + ((n & 1) << 2);   \
        _Pragma("unroll") for (int u = 0; u < 2; ++u) {                         \
            floatx4 s; s[0]=0.f; s[1]=0.f; s[2]=0.f; s[3]=0.f;                  \
            s = __builtin_amdgcn_mfma_f32_16x16x32_f16(ka0, qb[u][0], s, 0, 0, 0); \
            s = __builtin_amdgcn_mfma_f32_16x16x32_f16(ka1, qb[u][1], s, 0, 0, 0); \
            float p[4];                                                         \
            if (tail_) {                                                        \
                _Pragma("unroll") for (int r = 0; r < 4; ++r)                   \
                    p[r] = FEXP2((kb + r < count) ? s[r] : -1.0e4f);            \
            } else {                                                            \
                _Pragma("unroll") for (int r = 0; r < 4; ++r)                   \
                    p[r] = FEXP2(s[r]);                                         \
            }                                                                   \
            auto t0_ = __builtin_amdgcn_cvt_pkrtz(p[0], p[1]);                  \
            auto t1_ = __builtin_amdgcn_cvt_pkrtz(p[2], p[3]);                  \
            pbu[u][n >> 1][(n & 1) * 2 + 0] = __builtin_bit_cast(u32, t0_);     \
            pbu[u][n >> 1][(n & 1) * 2 + 1] = __builtin_bit_cast(u32, t1_);     \
        }                                                                       \
    }                                                                           \
    _Pragma("unroll") for (int wb = 0; wb < 4; ++wb) {                          \
        _Pragma("unroll") for (int m = 0; m < 2; ++m) {                         \
            f16x8 va = *(const f16x8*)&Vs[BUF][wb * 16 + lx][((m * 4 + quad) ^ swz) * 8]; \
            _Pragma("unroll") for (int u = 0; u < 2; ++u)                       \
                o[u][wb] = __builtin_amdgcn_mfma_f32_16x16x32_f16(              \
                    va, __builtin_bit_cast(f16x8, pbu[u][m]), o[u][wb], 0, 0, 0); \
        }                                                                       \
    }                                                                           \
    _Pragma("unroll") for (int m = 0; m < 2; ++m)                               \
        _Pragma("unroll") for (int u = 0; u < 2; ++u)                           \
            o1[u] = __builtin_amdgcn_mfma_f32_16x16x32_f16(                     \
                ones8, __builtin_bit_cast(f16x8, pbu[u][m]), o1[u], 0, 0, 0);   \
    } while (0)

__global__ __launch_bounds__(256) void attn_kernel(
    const f16* __restrict__ Q, const f16* __restrict__ Kc,
    const f16* __restrict__ Vct, const int* __restrict__ cnt,
    float* __restrict__ out)
{
    __shared__ f16 Ks[2][64][64];   // [buf][perm key][k]  swizzled 16B chunks
    __shared__ f16 Vs[2][64][64];   // [buf][w][key]       swizzled 16B chunks

    const int tid  = threadIdx.x;
    const int lane = tid & 63;
    const int wid  = tid >> 6;
    const int lx   = lane & 15;
    const int quad = lane >> 4;
    const int qt = blockIdx.x, h = blockIdx.y, bb = blockIdx.z;

    const int count = cnt[bb * 4 + 0];
    const int scp   = cnt[bb * 4 + 1];
    const int ntile = scp >> 6;

    const size_t hoff = ((size_t)(bb * H_NUM + h)) * S_LEN * W_DIM;
    const f16* Qg = Q + hoff + (size_t)qt * 128 * W_DIM;
    const f16* Kg = Kc + hoff;
    const f16* Vg = Vct + hoff;

    f16x8 qb[2][2];
#pragma unroll
    for (int u = 0; u < 2; ++u) {
        int qrow = u * 64 + wid * 16 + lx;
        qb[u][0] = *(const f16x8*)&Qg[(size_t)qrow * W_DIM + quad * 8];
        qb[u][1] = *(const f16x8*)&Qg[(size_t)qrow * W_DIM + 32 + quad * 8];
    }

    const f16x8 ones8 = {(f16)1.f, (f16)1.f, (f16)1.f, (f16)1.f,
                         (f16)1.f, (f16)1.f, (f16)1.f, (f16)1.f};

    floatx4 o[2][4];
    floatx4 o1[2];
#pragma unroll
    for (int u = 0; u < 2; ++u) {
        o1[u][0]=0.f; o1[u][1]=0.f; o1[u][2]=0.f; o1[u][3]=0.f;
#pragma unroll
        for (int wb = 0; wb < 4; ++wb) { o[u][wb][0]=0.f; o[u][wb][1]=0.f; o[u][wb][2]=0.f; o[u][wb][3]=0.f; }
    }

    const int swz = lx & 7;                    // read-side de-swizzle key

    // prologue: stage tile 0, wait, sync
    ASTAGE(0, 0);
    asm volatile("s_waitcnt vmcnt(0)" ::: "memory");
    __builtin_amdgcn_s_barrier();

    // steady state: stage t+1 under compute t  (all guards block-uniform)
    for (int t = 0; t < ntile; t += 2) {
        if (t + 1 < ntile) ASTAGE(1, (t + 1) * 64);
        ACOMPUTE(0, t * 64);
        asm volatile("s_waitcnt vmcnt(0)" ::: "memory");
        __builtin_amdgcn_s_barrier();
        if (t + 1 < ntile) {
            if (t + 2 < ntile) ASTAGE(0, (t + 2) * 64);
            ACOMPUTE(1, (t + 1) * 64);
            asm volatile("s_waitcnt vmcnt(0)" ::: "memory");
            __builtin_amdgcn_s_barrier();
        }
    }

#pragma unroll
    for (int u = 0; u < 2; ++u) {
        // o1 rows are all identical key-sums (ones A-operand); element 0 is
        // this lane's full denominator for its q. No cross-lane reduce.
        const float rl = 1.0f / o1[u][0];
        const int q = qt * 128 + u * 64 + wid * 16 + lx;
        const size_t base = ((size_t)bb * S_LEN + q) * D_DIM + h * W_DIM;
#pragma unroll
        for (int wb = 0; wb < 4; ++wb) {
            f4 r;
            r.x = o[u][wb][0] * rl;
            r.y = o[u][wb][1] * rl;
            r.z = o[u][wb][2] * rl;
            r.w = o[u][wb][3] * rl;
            *(f4*)&out[base + wb * 16 + quad * 4] = r;
        }
    }
}

// ---------------------------------------------------------------------------
extern "C" void kernel_launch(void* const* d_in, const int* in_sizes, int n_in,
                              void* d_out, int out_size, void* d_ws, size_t ws_size,
                              hipStream_t stream)
{
    const float* x    = (const float*)d_in[0];
    const float* Wq   = (const float*)d_in[1];
    const float* bq   = (const float*)d_in[2];
    const float* Wk   = (const float*)d_in[3];
    const float* bk   = (const float*)d_in[4];
    const float* Wv   = (const float*)d_in[5];
    const float* bv   = (const float*)d_in[6];
    const int*   mask = (const int*)d_in[7];
    float* out = (float*)d_out;

    const size_t per = (size_t)B_NUM * H_NUM * S_LEN * W_DIM;  // 8,388,608
    f16*   Q      = (f16*)d_ws;
    f16*   Kc     = Q + per;
    f16*   Vct    = Kc + per;
    f16*   x16    = Vct + per;
    f16*   wt16   = x16 + (size_t)(B_NUM * S_LEN) * D_DIM;
    int*   cnt    = (int*)(wt16 + (size_t)3 * D_DIM * D_DIM);
    short* fwdmap = (short*)(cnt + 4 * B_NUM);

    prep_kernel<<<4 + TR_BLOCKS + CAST_BLOCKS, 256, 0, stream>>>(
        mask, fwdmap, cnt, Wq, Wk, Wv, wt16, x, x16);
    qkv_mfma_kernel<<<dim3(24, 64), 256, 0, stream>>>(
        x16, wt16, bq, bk, bv, fwdmap, cnt, Q, Kc, Vct);
    attn_kernel<<<dim3(S_LEN / 128, H_NUM, B_NUM), 256, 0, stream>>>(
        Q, Kc, Vct, cnt, out);
}